// Round 4
// baseline (2086.779 us; speedup 1.0000x reference)
//
#include <hip/hip_runtime.h>
#include <hip/hip_bf16.h>
#include <stdint.h>

#define D_IN    1408
#define D_HID   256
#define N_HEADS 32
#define BATCH   16384

#define BM 128
#define BN 128            // half of one head's 256 hidden units
#define BK 64
#define KTILES (D_IN / BK)   // 22, exact

typedef unsigned short u16;
typedef short short8 __attribute__((ext_vector_type(8)));
typedef float f32x4 __attribute__((ext_vector_type(4)));

// ALL inputs and the output are float32 (reference dtypes). R1-R3 read them
// as bf16 bit-streams -> NaN. Internal compute: bf16 MFMA (threshold 2.4e-2).
__device__ __forceinline__ u16 f2b(float f) {
  __hip_bfloat16 h = __float2bfloat16(f);
  return *(u16*)&h;
}

// ---------------------------------------------------------------------------
// Kernel 0: X f32 [16384][1408] -> Xb bf16
// ---------------------------------------------------------------------------
__global__ void convert_x(const float4* __restrict__ X, ushort4* __restrict__ Xb) {
  int i = blockIdx.x * blockDim.x + threadIdx.x;   // 5,767,168 float4s exactly
  float4 v = X[i];
  ushort4 o;
  o.x = f2b(v.x); o.y = f2b(v.y); o.z = f2b(v.z); o.w = f2b(v.w);
  Xb[i] = o;
}

// ---------------------------------------------------------------------------
// Kernel 1: W1 f32 [32][1408][256] -> W1T bf16 [32][256][1408]
// ---------------------------------------------------------------------------
__global__ void transpose_w1(const float* __restrict__ W1, u16* __restrict__ W1T) {
  __shared__ u16 tile[64][65];
  const int h = blockIdx.z;
  const int f0 = blockIdx.x * 64;   // 22 tiles over 1408
  const int o0 = blockIdx.y * 64;   // 4 tiles over 256
  const int tx = threadIdx.x;       // 0..63
  const int ty = threadIdx.y;       // 0..3
  const size_t ib = (size_t)h * D_IN * D_HID;
  #pragma unroll
  for (int i = ty; i < 64; i += 4)
    tile[i][tx] = f2b(W1[ib + (size_t)(f0 + i) * D_HID + o0 + tx]);
  __syncthreads();
  const size_t ob = (size_t)h * D_HID * D_IN;
  #pragma unroll
  for (int i = ty; i < 64; i += 4)
    W1T[ob + (size_t)(o0 + i) * D_IN + f0 + tx] = tile[tx][i];
}

// ---------------------------------------------------------------------------
// Kernel 2: fused GEMM + relu + layer-2 partial reduction
// grid (128, 64): x = M-tile, y = head*2 + half
// Staging: VGPR round-trip (global_load_dwordx4 -> ds_write_b128), XOR-swizzled
// LDS layout: chunk ci=(row*8+pos) holds global [row][k8 = pos ^ (row&7)]
// (8 bf16) so fragment ds_read_b128 is bank-conflict-free.
// ---------------------------------------------------------------------------
__global__ __launch_bounds__(256, 3) void mano_gemm(
    const u16* __restrict__ X,               // [16384][1408] bf16 (ws)
    const u16* __restrict__ W1T,             // [32][256][1408] bf16 (ws)
    const float* __restrict__ b1,            // [32][256] f32
    const float* __restrict__ W2,            // [32][256][3] f32
    float* __restrict__ part)                // [16384][96] f32 (ws)
{
  __shared__ __align__(16) u16 As[BM * BK];  // 16 KB: 1024 chunks of 16B
  __shared__ __align__(16) u16 Bs[BN * BK];

  const int tid  = threadIdx.x;
  const int lane = tid & 63;
  const int wid  = tid >> 6;       // 0..3
  const int wave_m = wid >> 1;     // 0..1 (64-row band)
  const int wave_n = wid & 1;      // 0..1 (64-col band)
  const int quad = lane >> 4;
  const int l15  = lane & 15;

  const int m0   = blockIdx.x * BM;
  const int head = blockIdx.y >> 1;
  const int half = blockIdx.y & 1;

  const u16* Abase = X + (size_t)m0 * D_IN;
  const u16* Bbase = W1T + ((size_t)head * D_HID + half * BN) * D_IN;

  // each thread stages 4 chunks per tile: ci = c*256 + tid
  const u16* aptr[4];
  const u16* bptr[4];
  u16* asdst[4];
  u16* bsdst[4];
  #pragma unroll
  for (int c = 0; c < 4; ++c) {
    int ci  = c * 256 + tid;
    int row = ci >> 3;
    int k8  = (ci & 7) ^ (row & 7);          // XOR swizzle
    aptr[c] = Abase + (size_t)row * D_IN + k8 * 8;
    bptr[c] = Bbase + (size_t)row * D_IN + k8 * 8;
    asdst[c] = As + ci * 8;
    bsdst[c] = Bs + ci * 8;
  }

  f32x4 acc[4][4];
  #pragma unroll
  for (int i = 0; i < 4; ++i)
    #pragma unroll
    for (int j = 0; j < 4; ++j)
      acc[i][j] = f32x4{0.f, 0.f, 0.f, 0.f};

  int arow[4], brow[4];
  #pragma unroll
  for (int i = 0; i < 4; ++i) {
    arow[i] = wave_m * 64 + i * 16 + l15;
    brow[i] = wave_n * 64 + i * 16 + l15;
  }

  for (int kt = 0; kt < KTILES; ++kt) {
    const int kb = kt * BK;
    // issue global loads before the barrier: overlaps prev tile's drain
    uint4 va[4], vb[4];
    #pragma unroll
    for (int c = 0; c < 4; ++c) {
      va[c] = *(const uint4*)(aptr[c] + kb);
      vb[c] = *(const uint4*)(bptr[c] + kb);
    }
    __syncthreads();   // previous iter's LDS reads done before overwrite
    #pragma unroll
    for (int c = 0; c < 4; ++c) {
      *(uint4*)asdst[c] = va[c];
      *(uint4*)bsdst[c] = vb[c];
    }
    __syncthreads();

    #pragma unroll
    for (int ks = 0; ks < 2; ++ks) {
      short8 af[4], bfr[4];
      #pragma unroll
      for (int i = 0; i < 4; ++i) {
        int k8a = (ks * 4 + quad) ^ (arow[i] & 7);
        af[i]  = *(const short8*)((const char*)As + arow[i] * 128 + k8a * 16);
        int k8b = (ks * 4 + quad) ^ (brow[i] & 7);
        bfr[i] = *(const short8*)((const char*)Bs + brow[i] * 128 + k8b * 16);
      }
      #pragma unroll
      for (int i = 0; i < 4; ++i)
        #pragma unroll
        for (int j = 0; j < 4; ++j)
          acc[i][j] = __builtin_amdgcn_mfma_f32_16x16x32_bf16(af[i], bfr[j], acc[i][j], 0, 0, 0);
    }
  }

  // ---- fused epilogue: relu(acc + b1) . W2  -> partial sums ----
  // acc[i][j] elem (quad,r): row = m0+wave_m*64+i*16+quad*4+r, col = brow[j]
  const float* b1h = b1 + head * D_HID + half * BN;
  const float* W2h = W2 + ((size_t)head * D_HID + half * BN) * 3;

  float b1v[4], w2v[4][3];
  #pragma unroll
  for (int j = 0; j < 4; ++j) {
    int n = brow[j];
    b1v[j] = b1h[n];
    #pragma unroll
    for (int p = 0; p < 3; ++p)
      w2v[j][p] = W2h[n * 3 + p];
  }

  #pragma unroll
  for (int i = 0; i < 4; ++i) {
    float ps[4][3];
    #pragma unroll
    for (int r = 0; r < 4; ++r)
      #pragma unroll
      for (int p = 0; p < 3; ++p) ps[r][p] = 0.f;

    #pragma unroll
    for (int j = 0; j < 4; ++j)
      #pragma unroll
      for (int r = 0; r < 4; ++r) {
        float h = acc[i][j][r] + b1v[j];
        h = h > 0.f ? h : 0.f;
        #pragma unroll
        for (int p = 0; p < 3; ++p)
          ps[r][p] = fmaf(h, w2v[j][p], ps[r][p]);
      }

    // reduce over the 16 column-lanes (xor over low 4 lane bits stays in-quad)
    #pragma unroll
    for (int mask = 1; mask < 16; mask <<= 1)
      #pragma unroll
      for (int r = 0; r < 4; ++r)
        #pragma unroll
        for (int p = 0; p < 3; ++p)
          ps[r][p] += __shfl_xor(ps[r][p], mask, 64);

    if (l15 == 0) {
      int row = m0 + wave_m * 64 + i * 16 + quad * 4;
      #pragma unroll
      for (int r = 0; r < 4; ++r)
        #pragma unroll
        for (int p = 0; p < 3; ++p)
          atomicAdd(&part[(size_t)(row + r) * (N_HEADS * 3) + head * 3 + p], ps[r][p]);
    }
  }
}

// ---------------------------------------------------------------------------
// Kernel 3: out (f32) = part + b2
// ---------------------------------------------------------------------------
__global__ void finalize(const float* __restrict__ part,
                         const float* __restrict__ b2,
                         float* __restrict__ out, int total) {
  int i = blockIdx.x * blockDim.x + threadIdx.x;
  if (i < total)
    out[i] = part[i] + b2[i % (N_HEADS * 3)];
}

extern "C" void kernel_launch(void* const* d_in, const int* in_sizes, int n_in,
                              void* d_out, int out_size, void* d_ws, size_t ws_size,
                              hipStream_t stream) {
  const float* X  = (const float*)d_in[0];
  const float* W1 = (const float*)d_in[1];
  const float* b1 = (const float*)d_in[2];
  const float* W2 = (const float*)d_in[3];
  const float* b2 = (const float*)d_in[4];

  // ws layout: Xb 46,137,344 B | W1T 23,068,672 B | part 6,291,456 B = 75.5 MB
  u16*   Xb   = (u16*)d_ws;
  u16*   W1T  = (u16*)((char*)d_ws + (size_t)BATCH * D_IN * 2);
  float* part = (float*)((char*)d_ws + (size_t)BATCH * D_IN * 2
                                     + (size_t)N_HEADS * D_IN * D_HID * 2);

  hipMemsetAsync(part, 0, (size_t)BATCH * N_HEADS * 3 * sizeof(float), stream);

  convert_x<<<(BATCH * D_IN / 4) / 256, 256, 0, stream>>>(
      (const float4*)X, (ushort4*)Xb);

  transpose_w1<<<dim3(D_IN / 64, D_HID / 64, N_HEADS), dim3(64, 4), 0, stream>>>(W1, W1T);

  mano_gemm<<<dim3(BATCH / BM, N_HEADS * 2), 256, 0, stream>>>(Xb, W1T, b1, W2, part);

  const int total = BATCH * N_HEADS * 3;
  finalize<<<(total + 255) / 256, 256, 0, stream>>>(part, b2, (float*)d_out, total);
}

// Round 6
// 2079.233 us; speedup vs baseline: 1.0036x; 1.0036x over previous
//
#include <hip/hip_runtime.h>
#include <hip/hip_bf16.h>
#include <stdint.h>

#define D_IN    1408
#define D_HID   256
#define N_HEADS 32
#define BATCH   16384

#define BM 64             // rows per block
#define BN 256            // full head of hidden units
#define BK 64
#define KTILES (D_IN / BK)   // 22, exact

typedef unsigned short u16;
typedef short short8 __attribute__((ext_vector_type(8)));
typedef float f32x4 __attribute__((ext_vector_type(4)));

// All inputs and the output are float32 (reference dtypes); compute is bf16
// MFMA (absmax 7.8e-3 vs threshold 2.4e-2, verified R4).
__device__ __forceinline__ u16 f2b(float f) {
  __hip_bfloat16 h = __float2bfloat16(f);
  return *(u16*)&h;
}

// ---------------------------------------------------------------------------
// Kernel 0: X f32 [16384][1408] -> Xb bf16
// ---------------------------------------------------------------------------
__global__ void convert_x(const float4* __restrict__ X, ushort4* __restrict__ Xb) {
  int i = blockIdx.x * blockDim.x + threadIdx.x;   // 5,767,168 float4s exactly
  float4 v = X[i];
  ushort4 o;
  o.x = f2b(v.x); o.y = f2b(v.y); o.z = f2b(v.z); o.w = f2b(v.w);
  Xb[i] = o;
}

// ---------------------------------------------------------------------------
// Kernel 1: W1 f32 [32][1408][256] -> W1T bf16 [32][256][1408]
// ---------------------------------------------------------------------------
__global__ void transpose_w1(const float* __restrict__ W1, u16* __restrict__ W1T) {
  __shared__ u16 tile[64][65];
  const int h = blockIdx.z;
  const int f0 = blockIdx.x * 64;
  const int o0 = blockIdx.y * 64;
  const int tx = threadIdx.x;       // 0..63
  const int ty = threadIdx.y;       // 0..3
  const size_t ib = (size_t)h * D_IN * D_HID;
  #pragma unroll
  for (int i = ty; i < 64; i += 4)
    tile[i][tx] = f2b(W1[ib + (size_t)(f0 + i) * D_HID + o0 + tx]);
  __syncthreads();
  const size_t ob = (size_t)h * D_HID * D_IN;
  #pragma unroll
  for (int i = ty; i < 64; i += 4)
    W1T[ob + (size_t)(o0 + i) * D_IN + f0 + tx] = tile[tx][i];
}

// ---------------------------------------------------------------------------
// Kernel 2: fused GEMM + relu + layer-2 reduction, FULL head per block.
// Tile 64x256: 4 waves, wave w owns cols w*64..w*64+63. Block owns ALL of
// n=256 for its 64 rows -> writes FINAL out directly (+b2). No atomics
// (R4: fp32 atomicAdd = CAS write-through = 5.88 GB), no inter-block
// partials (R5: doubled ws `part` was the prime failure suspect).
// ws use: Xb+W1T = 69.2 MB < R4-proven 75.5 MB.
// grid 8192 1-D, XCD-swizzled: xcd=id&7 owns heads 4*xcd..4*xcd+3
// (W1T slice 2.9 MB -> L2-resident); consecutive slots share one X band.
// ---------------------------------------------------------------------------
__global__ __launch_bounds__(256, 3) void mano_gemm(
    const u16* __restrict__ X,               // [16384][1408] bf16 (ws)
    const u16* __restrict__ W1T,             // [32][256][1408] bf16 (ws)
    const float* __restrict__ b1,            // [32][256] f32
    const float* __restrict__ W2,            // [32][256][3] f32
    const float* __restrict__ b2,            // [32][3] f32
    float* __restrict__ out)                 // [16384][96] f32 (d_out)
{
  __shared__ __align__(16) u16 As[BM * BK];  // 8 KB; reused as f32 scratch later
  __shared__ __align__(16) u16 Bs[BN * BK];  // 32 KB

  const int tid  = threadIdx.x;
  const int lane = tid & 63;
  const int wid  = tid >> 6;       // 0..3 = wave_n (64-col band)
  const int quad = lane >> 4;
  const int l15  = lane & 15;

  // XCD-aware decode (perf-only; bijection id <-> (mtile, head)):
  const int id    = blockIdx.x;
  const int xcd   = id & 7;
  const int s     = id >> 3;           // 0..1023 per XCD
  const int head  = xcd * 4 + (s & 3); // this XCD's 4 heads
  const int mtile = s >> 2;            // 0..255
  const int m0    = mtile * BM;

  const u16* Abase = X + (size_t)m0 * D_IN;
  const u16* Bbase = W1T + (size_t)head * D_HID * D_IN;

  // staging: LDS chunk ci (16B) holds global [row=ci>>3][k8=(ci&7)^(row&7)]
  // (XOR swizzle -> conflict-free ds_read_b128). A: 512 chunks, B: 2048.
  const u16* aptr[2];
  u16* asdst[2];
  #pragma unroll
  for (int c = 0; c < 2; ++c) {
    int ci  = c * 256 + tid;
    int row = ci >> 3;
    int k8  = (ci & 7) ^ (row & 7);
    aptr[c]  = Abase + (size_t)row * D_IN + k8 * 8;
    asdst[c] = As + ci * 8;
  }
  const u16* bptr[8];
  u16* bsdst[8];
  #pragma unroll
  for (int c = 0; c < 8; ++c) {
    int ci  = c * 256 + tid;
    int row = ci >> 3;
    int k8  = (ci & 7) ^ (row & 7);
    bptr[c]  = Bbase + (size_t)row * D_IN + k8 * 8;
    bsdst[c] = Bs + ci * 8;
  }

  f32x4 acc[4][4];
  #pragma unroll
  for (int i = 0; i < 4; ++i)
    #pragma unroll
    for (int j = 0; j < 4; ++j)
      acc[i][j] = f32x4{0.f, 0.f, 0.f, 0.f};

  int arow[4], brow[4];
  #pragma unroll
  for (int i = 0; i < 4; ++i) {
    arow[i] = i * 16 + l15;              // 0..63
    brow[i] = wid * 64 + i * 16 + l15;   // 0..255
  }

  for (int kt = 0; kt < KTILES; ++kt) {
    const int kb = kt * BK;
    uint4 va[2], vb[8];
    #pragma unroll
    for (int c = 0; c < 2; ++c) va[c] = *(const uint4*)(aptr[c] + kb);
    #pragma unroll
    for (int c = 0; c < 8; ++c) vb[c] = *(const uint4*)(bptr[c] + kb);
    __syncthreads();
    #pragma unroll
    for (int c = 0; c < 2; ++c) *(uint4*)asdst[c] = va[c];
    #pragma unroll
    for (int c = 0; c < 8; ++c) *(uint4*)bsdst[c] = vb[c];
    __syncthreads();

    #pragma unroll
    for (int ks = 0; ks < 2; ++ks) {
      short8 af[4], bfr[4];
      #pragma unroll
      for (int i = 0; i < 4; ++i) {
        int k8a = (ks * 4 + quad) ^ (arow[i] & 7);
        af[i]  = *(const short8*)((const char*)As + arow[i] * 128 + k8a * 16);
        int k8b = (ks * 4 + quad) ^ (brow[i] & 7);
        bfr[i] = *(const short8*)((const char*)Bs + brow[i] * 128 + k8b * 16);
      }
      #pragma unroll
      for (int i = 0; i < 4; ++i)
        #pragma unroll
        for (int j = 0; j < 4; ++j)
          acc[i][j] = __builtin_amdgcn_mfma_f32_16x16x32_bf16(af[i], bfr[j], acc[i][j], 0, 0, 0);
    }
  }

  // ---- fused epilogue: relu(acc + b1) . W2, combine 4 waves via LDS ----
  // acc[i][j] elem (quad,r): row = m0 + i*16 + quad*4 + r, col n = brow[j]
  const float* b1h = b1 + head * D_HID;
  const float* W2h = W2 + (size_t)head * D_HID * 3;

  float b1v[4], w2v[4][3];
  #pragma unroll
  for (int j = 0; j < 4; ++j) {
    int n = brow[j];
    b1v[j] = b1h[n];
    #pragma unroll
    for (int p = 0; p < 3; ++p)
      w2v[j][p] = W2h[n * 3 + p];
  }

  __syncthreads();                 // all LDS tile reads done before scratch reuse
  float* scr = (float*)As;         // [wave][row 0..63][p 0..2] = 768 f32 (3 KB)

  #pragma unroll
  for (int i = 0; i < 4; ++i) {
    float ps[4][3];
    #pragma unroll
    for (int r = 0; r < 4; ++r)
      #pragma unroll
      for (int p = 0; p < 3; ++p) ps[r][p] = 0.f;

    #pragma unroll
    for (int j = 0; j < 4; ++j)
      #pragma unroll
      for (int r = 0; r < 4; ++r) {
        float h = acc[i][j][r] + b1v[j];
        h = h > 0.f ? h : 0.f;
        #pragma unroll
        for (int p = 0; p < 3; ++p)
          ps[r][p] = fmaf(h, w2v[j][p], ps[r][p]);
      }

    // sum over the 16 column-lanes (xor on low 4 lane bits stays in-quad)
    #pragma unroll
    for (int mask = 1; mask < 16; mask <<= 1)
      #pragma unroll
      for (int r = 0; r < 4; ++r)
        #pragma unroll
        for (int p = 0; p < 3; ++p)
          ps[r][p] += __shfl_xor(ps[r][p], mask, 64);

    if (l15 == 0) {
      int row = i * 16 + quad * 4;               // +r below
      #pragma unroll
      for (int r = 0; r < 4; ++r)
        #pragma unroll
        for (int p = 0; p < 3; ++p)
          scr[wid * 192 + (row + r) * 3 + p] = ps[r][p];
    }
  }
  __syncthreads();

  // 192 threads: final value = sum of 4 wave partials + b2 -> out
  if (tid < 192) {
    int rl = tid / 3, p = tid - rl * 3;          // rl 0..63
    float v = scr[rl * 3 + p] + scr[192 + rl * 3 + p]
            + scr[384 + rl * 3 + p] + scr[576 + rl * 3 + p]
            + b2[head * 3 + p];
    out[(size_t)(m0 + rl) * (N_HEADS * 3) + head * 3 + p] = v;
  }
}

extern "C" void kernel_launch(void* const* d_in, const int* in_sizes, int n_in,
                              void* d_out, int out_size, void* d_ws, size_t ws_size,
                              hipStream_t stream) {
  const float* X  = (const float*)d_in[0];
  const float* W1 = (const float*)d_in[1];
  const float* b1 = (const float*)d_in[2];
  const float* W2 = (const float*)d_in[3];
  const float* b2 = (const float*)d_in[4];

  // ws: Xb 46,137,344 | W1T 23,068,672  = 69,206,016 B (< R4-proven 75.5 MB)
  u16* Xb  = (u16*)d_ws;
  u16* W1T = (u16*)((char*)d_ws + (size_t)BATCH * D_IN * 2);

  convert_x<<<(BATCH * D_IN / 4) / 256, 256, 0, stream>>>(
      (const float4*)X, (ushort4*)Xb);

  transpose_w1<<<dim3(D_IN / 64, D_HID / 64, N_HEADS), dim3(64, 4), 0, stream>>>(W1, W1T);

  mano_gemm<<<dim3(BATCH / BM * N_HEADS), 256, 0, stream>>>(
      Xb, W1T, b1, W2, b2, (float*)d_out);
}

// Round 8
// 592.507 us; speedup vs baseline: 3.5219x; 3.5092x over previous
//
#include <hip/hip_runtime.h>
#include <hip/hip_bf16.h>
#include <stdint.h>

#define D_IN    1408
#define D_HID   256
#define N_HEADS 32
#define BATCH   16384

#define BM 64             // rows per block
#define BN 256            // full head of hidden units
#define BK 64
#define KTILES (D_IN / BK)   // 22, exact

typedef unsigned short u16;
typedef short short8 __attribute__((ext_vector_type(8)));
typedef float f32x4 __attribute__((ext_vector_type(4)));

// All inputs and the output are float32 (reference dtypes); compute is bf16
// MFMA (absmax 7.8e-3 vs threshold 2.4e-2, verified R4/R6/R7-first-launch).
__device__ __forceinline__ u16 f2b(float f) {
  __hip_bfloat16 h = __float2bfloat16(f);
  return *(u16*)&h;
}

// async global->LDS DMA, 16B/lane; LDS dest = wave-uniform base + lane*16.
// No data VGPRs -> no scratch spill (R6's 5.6 GB WRITE_SIZE was spilled
// uint4 prefetch regs; removing them was R7's 1965->587 us win).
__device__ __forceinline__ void gload_lds16(const void* g, void* l) {
  __builtin_amdgcn_global_load_lds(
      (const __attribute__((address_space(1))) uint32_t*)((const uint32_t*)g),
      (__attribute__((address_space(3))) uint32_t*)((uint32_t*)l),
      16, 0, 0);
}

// ---------------------------------------------------------------------------
// Kernel 0: X f32 [16384][1408] -> Xb bf16
// ---------------------------------------------------------------------------
__global__ void convert_x(const float4* __restrict__ X, ushort4* __restrict__ Xb) {
  int i = blockIdx.x * blockDim.x + threadIdx.x;   // 5,767,168 float4s exactly
  float4 v = X[i];
  ushort4 o;
  o.x = f2b(v.x); o.y = f2b(v.y); o.z = f2b(v.z); o.w = f2b(v.w);
  Xb[i] = o;
}

// ---------------------------------------------------------------------------
// Kernel 1: W1 f32 [32][1408][256] -> W1T bf16 [32][256][1408]
// ---------------------------------------------------------------------------
__global__ void transpose_w1(const float* __restrict__ W1, u16* __restrict__ W1T) {
  __shared__ u16 tile[64][65];
  const int h = blockIdx.z;
  const int f0 = blockIdx.x * 64;
  const int o0 = blockIdx.y * 64;
  const int tx = threadIdx.x;       // 0..63
  const int ty = threadIdx.y;       // 0..3
  const size_t ib = (size_t)h * D_IN * D_HID;
  #pragma unroll
  for (int i = ty; i < 64; i += 4)
    tile[i][tx] = f2b(W1[ib + (size_t)(f0 + i) * D_HID + o0 + tx]);
  __syncthreads();
  const size_t ob = (size_t)h * D_HID * D_IN;
  #pragma unroll
  for (int i = ty; i < 64; i += 4)
    W1T[ob + (size_t)(o0 + i) * D_IN + f0 + tx] = tile[tx][i];
}

// ---------------------------------------------------------------------------
// Kernel 2: fused GEMM + relu + layer-2 reduction, FULL head per block.
// Tile 64x256: 4 waves, wave w owns cols w*64..w*64+63; block writes FINAL
// out (+b2). Staging via global_load_lds + EXPLICIT vmcnt(0) drain before the
// consume barrier (R7 raced intermittently: __syncthreads' workgroup fence is
// not guaranteed to drain the DMA's vmcnt-tracked LDS writes).
// grid 8192 1-D, XCD-swizzled: xcd=id&7 owns heads 4*xcd..4*xcd+3
// (W1T slice 2.9 MB -> L2-resident).
// ---------------------------------------------------------------------------
__global__ __launch_bounds__(256, 3) void mano_gemm(
    const u16* __restrict__ X,               // [16384][1408] bf16 (ws)
    const u16* __restrict__ W1T,             // [32][256][1408] bf16 (ws)
    const float* __restrict__ b1,            // [32][256] f32
    const float* __restrict__ W2,            // [32][256][3] f32
    const float* __restrict__ b2,            // [32][3] f32
    float* __restrict__ out)                 // [16384][96] f32 (d_out)
{
  __shared__ __align__(16) u16 As[BM * BK];  // 8 KB; reused as f32 scratch later
  __shared__ __align__(16) u16 Bs[BN * BK];  // 32 KB

  const int tid  = threadIdx.x;
  const int lane = tid & 63;
  const int wid  = tid >> 6;       // 0..3 = wave_n (64-col band)
  const int quad = lane >> 4;
  const int l15  = lane & 15;

  // XCD-aware decode (perf-only; bijection id <-> (mtile, head)):
  const int id    = blockIdx.x;
  const int xcd   = id & 7;
  const int s     = id >> 3;           // 0..1023 per XCD
  const int head  = xcd * 4 + (s & 3); // this XCD's 4 heads
  const int mtile = s >> 2;            // 0..255
  const int m0    = mtile * BM;

  const u16* Abase = X + (size_t)m0 * D_IN;
  const u16* Bbase = W1T + (size_t)head * D_HID * D_IN;

  // staging: LDS chunk ci (16B) holds global [row=ci>>3][k8=(ci&7)^(row&7)]
  // (XOR swizzle -> conflict-free ds_read_b128). DMA assignment:
  // ci = c*256 + wid*64 + lane (LDS base wave-uniform, HW adds lane*16).
  const u16* aptr[2];
  u16* asdst[2];
  #pragma unroll
  for (int c = 0; c < 2; ++c) {
    int ci  = c * 256 + wid * 64 + lane;
    int row = ci >> 3;
    int k8  = (ci & 7) ^ (row & 7);
    aptr[c]  = Abase + (size_t)row * D_IN + k8 * 8;
    asdst[c] = As + (c * 256 + wid * 64) * 8;   // wave-uniform
  }
  const u16* bptr[8];
  u16* bsdst[8];
  #pragma unroll
  for (int c = 0; c < 8; ++c) {
    int ci  = c * 256 + wid * 64 + lane;
    int row = ci >> 3;
    int k8  = (ci & 7) ^ (row & 7);
    bptr[c]  = Bbase + (size_t)row * D_IN + k8 * 8;
    bsdst[c] = Bs + (c * 256 + wid * 64) * 8;   // wave-uniform
  }

  f32x4 acc[4][4];
  #pragma unroll
  for (int i = 0; i < 4; ++i)
    #pragma unroll
    for (int j = 0; j < 4; ++j)
      acc[i][j] = f32x4{0.f, 0.f, 0.f, 0.f};

  int arow[4], brow[4];
  #pragma unroll
  for (int i = 0; i < 4; ++i) {
    arow[i] = i * 16 + l15;              // 0..63
    brow[i] = wid * 64 + i * 16 + l15;   // 0..255
  }

  for (int kt = 0; kt < KTILES; ++kt) {
    const int kb = kt * BK;
    __syncthreads();   // previous iter's LDS reads done before DMA overwrite
    #pragma unroll
    for (int c = 0; c < 2; ++c) gload_lds16(aptr[c] + kb, asdst[c]);
    #pragma unroll
    for (int c = 0; c < 8; ++c) gload_lds16(bptr[c] + kb, bsdst[c]);
    // EXPLICIT drain of the DMA's vmcnt-tracked LDS writes. 0x0F70 =
    // vmcnt(0), expcnt/lgkmcnt masked off. __syncthreads alone raced (R7).
    __builtin_amdgcn_s_waitcnt(0x0F70);
    __syncthreads();

    #pragma unroll
    for (int ks = 0; ks < 2; ++ks) {
      short8 af[4], bfr[4];
      #pragma unroll
      for (int i = 0; i < 4; ++i) {
        int k8a = (ks * 4 + quad) ^ (arow[i] & 7);
        af[i]  = *(const short8*)((const char*)As + arow[i] * 128 + k8a * 16);
        int k8b = (ks * 4 + quad) ^ (brow[i] & 7);
        bfr[i] = *(const short8*)((const char*)Bs + brow[i] * 128 + k8b * 16);
      }
      #pragma unroll
      for (int i = 0; i < 4; ++i)
        #pragma unroll
        for (int j = 0; j < 4; ++j)
          acc[i][j] = __builtin_amdgcn_mfma_f32_16x16x32_bf16(af[i], bfr[j], acc[i][j], 0, 0, 0);
    }
  }

  // ---- fused epilogue: relu(acc + b1) . W2, combine 4 waves via LDS ----
  // acc[i][j] elem (quad,r): row = m0 + i*16 + quad*4 + r, col n = brow[j]
  const float* b1h = b1 + head * D_HID;
  const float* W2h = W2 + (size_t)head * D_HID * 3;

  float b1v[4], w2v[4][3];
  #pragma unroll
  for (int j = 0; j < 4; ++j) {
    int n = brow[j];
    b1v[j] = b1h[n];
    #pragma unroll
    for (int p = 0; p < 3; ++p)
      w2v[j][p] = W2h[n * 3 + p];
  }

  __syncthreads();                 // all LDS tile reads done before scratch reuse
  float* scr = (float*)As;         // [wave][row 0..63][p 0..2] = 768 f32 (3 KB)

  #pragma unroll
  for (int i = 0; i < 4; ++i) {
    float ps[4][3];
    #pragma unroll
    for (int r = 0; r < 4; ++r)
      #pragma unroll
      for (int p = 0; p < 3; ++p) ps[r][p] = 0.f;

    #pragma unroll
    for (int j = 0; j < 4; ++j)
      #pragma unroll
      for (int r = 0; r < 4; ++r) {
        float h = acc[i][j][r] + b1v[j];
        h = h > 0.f ? h : 0.f;
        #pragma unroll
        for (int p = 0; p < 3; ++p)
          ps[r][p] = fmaf(h, w2v[j][p], ps[r][p]);
      }

    // sum over the 16 column-lanes (xor on low 4 lane bits stays in-quad)
    #pragma unroll
    for (int mask = 1; mask < 16; mask <<= 1)
      #pragma unroll
      for (int r = 0; r < 4; ++r)
        #pragma unroll
        for (int p = 0; p < 3; ++p)
          ps[r][p] += __shfl_xor(ps[r][p], mask, 64);

    if (l15 == 0) {
      int row = i * 16 + quad * 4;               // +r below
      #pragma unroll
      for (int r = 0; r < 4; ++r)
        #pragma unroll
        for (int p = 0; p < 3; ++p)
          scr[wid * 192 + (row + r) * 3 + p] = ps[r][p];
    }
  }
  __syncthreads();

  // 192 threads: final value = sum of 4 wave partials + b2 -> out
  if (tid < 192) {
    int rl = tid / 3, p = tid - rl * 3;          // rl 0..63
    float v = scr[rl * 3 + p] + scr[192 + rl * 3 + p]
            + scr[384 + rl * 3 + p] + scr[576 + rl * 3 + p]
            + b2[head * 3 + p];
    out[(size_t)(m0 + rl) * (N_HEADS * 3) + head * 3 + p] = v;
  }
}

extern "C" void kernel_launch(void* const* d_in, const int* in_sizes, int n_in,
                              void* d_out, int out_size, void* d_ws, size_t ws_size,
                              hipStream_t stream) {
  const float* X  = (const float*)d_in[0];
  const float* W1 = (const float*)d_in[1];
  const float* b1 = (const float*)d_in[2];
  const float* W2 = (const float*)d_in[3];
  const float* b2 = (const float*)d_in[4];

  // ws: Xb 46,137,344 | W1T 23,068,672  = 69,206,016 B (proven fits)
  u16* Xb  = (u16*)d_ws;
  u16* W1T = (u16*)((char*)d_ws + (size_t)BATCH * D_IN * 2);

  convert_x<<<(BATCH * D_IN / 4) / 256, 256, 0, stream>>>(
      (const float4*)X, (ushort4*)Xb);

  transpose_w1<<<dim3(D_IN / 64, D_HID / 64, N_HEADS), dim3(64, 4), 0, stream>>>(W1, W1T);

  mano_gemm<<<dim3(BATCH / BM * N_HEADS), 256, 0, stream>>>(
      Xb, W1T, b1, W2, b2, (float*)d_out);
}

// Round 9
// 592.163 us; speedup vs baseline: 3.5240x; 1.0006x over previous
//
#include <hip/hip_runtime.h>
#include <hip/hip_bf16.h>
#include <stdint.h>

#define D_IN    1408
#define D_HID   256
#define N_HEADS 32
#define BATCH   16384

#define BM 64             // rows per block
#define BN 256            // full head of hidden units
#define BK 64
#define KTILES (D_IN / BK)   // 22, exact

typedef unsigned short u16;
typedef short short8 __attribute__((ext_vector_type(8)));
typedef float f32x4 __attribute__((ext_vector_type(4)));

// All inputs and the output are float32 (reference dtypes); compute is bf16
// MFMA (absmax 7.8e-3 vs threshold 2.4e-2, verified R4/R6/R8).
__device__ __forceinline__ u16 f2b(float f) {
  __hip_bfloat16 h = __float2bfloat16(f);
  return *(u16*)&h;
}

// async global->LDS DMA, 16B/lane; LDS dest = wave-uniform base + lane*16.
// No data VGPRs -> no scratch spill (R6's 5.6 GB WRITE_SIZE was spilled
// uint4 prefetch regs; removing them was the 1965->587 us win).
__device__ __forceinline__ void gload_lds16(const void* g, void* l) {
  __builtin_amdgcn_global_load_lds(
      (const __attribute__((address_space(1))) uint32_t*)((const uint32_t*)g),
      (__attribute__((address_space(3))) uint32_t*)((uint32_t*)l),
      16, 0, 0);
}

// ---------------------------------------------------------------------------
// Kernel 0: X f32 [16384][1408] -> Xb bf16
// ---------------------------------------------------------------------------
__global__ void convert_x(const float4* __restrict__ X, ushort4* __restrict__ Xb) {
  int i = blockIdx.x * blockDim.x + threadIdx.x;   // 5,767,168 float4s exactly
  float4 v = X[i];
  ushort4 o;
  o.x = f2b(v.x); o.y = f2b(v.y); o.z = f2b(v.z); o.w = f2b(v.w);
  Xb[i] = o;
}

// ---------------------------------------------------------------------------
// Kernel 1: W1 f32 [32][1408][256] -> W1T bf16 [32][256][1408]
// ---------------------------------------------------------------------------
__global__ void transpose_w1(const float* __restrict__ W1, u16* __restrict__ W1T) {
  __shared__ u16 tile[64][65];
  const int h = blockIdx.z;
  const int f0 = blockIdx.x * 64;
  const int o0 = blockIdx.y * 64;
  const int tx = threadIdx.x;       // 0..63
  const int ty = threadIdx.y;       // 0..3
  const size_t ib = (size_t)h * D_IN * D_HID;
  #pragma unroll
  for (int i = ty; i < 64; i += 4)
    tile[i][tx] = f2b(W1[ib + (size_t)(f0 + i) * D_HID + o0 + tx]);
  __syncthreads();
  const size_t ob = (size_t)h * D_HID * D_IN;
  #pragma unroll
  for (int i = ty; i < 64; i += 4)
    W1T[ob + (size_t)(o0 + i) * D_IN + f0 + tx] = tile[tx][i];
}

// ---------------------------------------------------------------------------
// Kernel 2: fused GEMM + relu + layer-2 reduction, FULL head per block.
// Tile 64x256: 4 waves, wave w owns cols w*64..w*64+63; block writes FINAL
// out (+b2). Staging: global_load_lds + explicit vmcnt(0) drain (R7 raced
// without it). R8 counters: 132 regs/wave (68 arch + 64 acc) -> 3 waves/SIMD,
// Occupancy 33%. This rev: uniform SGPR bases + 32-bit per-lane offsets
// (kills 10 persistent 64-bit pointer VGPRs) + launch_bounds(256,4) ->
// <=128 regs -> 16 waves/CU, 4 blocks/CU (LDS 4x40KB = 160KB exact).
// grid 8192 1-D, XCD-swizzled: xcd=id&7 owns heads 4*xcd..4*xcd+3
// (W1T slice 2.9 MB -> L2-resident).
// ---------------------------------------------------------------------------
__global__ __launch_bounds__(256, 4) void mano_gemm(
    const u16* __restrict__ X,               // [16384][1408] bf16 (ws)
    const u16* __restrict__ W1T,             // [32][256][1408] bf16 (ws)
    const float* __restrict__ b1,            // [32][256] f32
    const float* __restrict__ W2,            // [32][256][3] f32
    const float* __restrict__ b2,            // [32][3] f32
    float* __restrict__ out)                 // [16384][96] f32 (d_out)
{
  __shared__ __align__(16) u16 As[BM * BK];  // 8 KB; reused as f32 scratch later
  __shared__ __align__(16) u16 Bs[BN * BK];  // 32 KB

  const int tid  = threadIdx.x;
  const int lane = tid & 63;
  const int wid  = tid >> 6;       // 0..3 = wave_n (64-col band)
  const int quad = lane >> 4;
  const int l15  = lane & 15;

  // XCD-aware decode (perf-only; bijection id <-> (mtile, head)):
  const int id    = blockIdx.x;
  const int xcd   = id & 7;
  const int s     = id >> 3;           // 0..1023 per XCD
  const int head  = xcd * 4 + (s & 3); // this XCD's 4 heads
  const int mtile = s >> 2;            // 0..255
  const int m0    = mtile * BM;

  // Wave-uniform bases (SGPRs), per-lane 32-bit offsets (1 VGPR each).
  const u16* Au = X + (size_t)m0 * D_IN;
  const u16* Bu = W1T + (size_t)head * D_HID * D_IN;

  // staging: LDS chunk ci (16B) holds global [row=ci>>3][k8=(ci&7)^(row&7)]
  // (XOR swizzle -> conflict-free ds_read_b128). DMA assignment:
  // ci = c*256 + wid*64 + lane (LDS base wave-uniform, HW adds lane*16).
  int aoff[2];
  #pragma unroll
  for (int c = 0; c < 2; ++c) {
    int ci  = c * 256 + wid * 64 + lane;
    int row = ci >> 3;
    int k8  = (ci & 7) ^ (row & 7);
    aoff[c] = row * D_IN + k8 * 8;
  }
  int boff[8];
  #pragma unroll
  for (int c = 0; c < 8; ++c) {
    int ci  = c * 256 + wid * 64 + lane;
    int row = ci >> 3;
    int k8  = (ci & 7) ^ (row & 7);
    boff[c] = row * D_IN + k8 * 8;
  }

  f32x4 acc[4][4];
  #pragma unroll
  for (int i = 0; i < 4; ++i)
    #pragma unroll
    for (int j = 0; j < 4; ++j)
      acc[i][j] = f32x4{0.f, 0.f, 0.f, 0.f};

  int arow[4], brow[4];
  #pragma unroll
  for (int i = 0; i < 4; ++i) {
    arow[i] = i * 16 + l15;              // 0..63
    brow[i] = wid * 64 + i * 16 + l15;   // 0..255
  }

  for (int kt = 0; kt < KTILES; ++kt) {
    const int kb = kt * BK;
    __syncthreads();   // previous iter's LDS reads done before DMA overwrite
    #pragma unroll
    for (int c = 0; c < 2; ++c)
      gload_lds16(Au + aoff[c] + kb, As + (c * 256 + wid * 64) * 8);
    #pragma unroll
    for (int c = 0; c < 8; ++c)
      gload_lds16(Bu + boff[c] + kb, Bs + (c * 256 + wid * 64) * 8);
    // EXPLICIT drain of the DMA's vmcnt-tracked LDS writes. 0x0F70 =
    // vmcnt(0), expcnt/lgkmcnt masked off. __syncthreads alone raced (R7).
    __builtin_amdgcn_s_waitcnt(0x0F70);
    __syncthreads();

    #pragma unroll
    for (int ks = 0; ks < 2; ++ks) {
      short8 af[4], bfr[4];
      #pragma unroll
      for (int i = 0; i < 4; ++i) {
        int k8a = (ks * 4 + quad) ^ (arow[i] & 7);
        af[i]  = *(const short8*)((const char*)As + arow[i] * 128 + k8a * 16);
        int k8b = (ks * 4 + quad) ^ (brow[i] & 7);
        bfr[i] = *(const short8*)((const char*)Bs + brow[i] * 128 + k8b * 16);
      }
      #pragma unroll
      for (int i = 0; i < 4; ++i)
        #pragma unroll
        for (int j = 0; j < 4; ++j)
          acc[i][j] = __builtin_amdgcn_mfma_f32_16x16x32_bf16(af[i], bfr[j], acc[i][j], 0, 0, 0);
    }
  }

  // ---- fused epilogue: relu(acc + b1) . W2, combine 4 waves via LDS ----
  // acc[i][j] elem (quad,r): row = m0 + i*16 + quad*4 + r, col n = brow[j]
  const float* b1h = b1 + head * D_HID;
  const float* W2h = W2 + (size_t)head * D_HID * 3;

  float b1v[4], w2v[4][3];
  #pragma unroll
  for (int j = 0; j < 4; ++j) {
    int n = brow[j];
    b1v[j] = b1h[n];
    #pragma unroll
    for (int p = 0; p < 3; ++p)
      w2v[j][p] = W2h[n * 3 + p];
  }

  __syncthreads();                 // all LDS tile reads done before scratch reuse
  float* scr = (float*)As;         // [wave][row 0..63][p 0..2] = 768 f32 (3 KB)

  #pragma unroll
  for (int i = 0; i < 4; ++i) {
    float ps[4][3];
    #pragma unroll
    for (int r = 0; r < 4; ++r)
      #pragma unroll
      for (int p = 0; p < 3; ++p) ps[r][p] = 0.f;

    #pragma unroll
    for (int j = 0; j < 4; ++j)
      #pragma unroll
      for (int r = 0; r < 4; ++r) {
        float h = acc[i][j][r] + b1v[j];
        h = h > 0.f ? h : 0.f;
        #pragma unroll
        for (int p = 0; p < 3; ++p)
          ps[r][p] = fmaf(h, w2v[j][p], ps[r][p]);
      }

    // sum over the 16 column-lanes (xor on low 4 lane bits stays in-quad)
    #pragma unroll
    for (int mask = 1; mask < 16; mask <<= 1)
      #pragma unroll
      for (int r = 0; r < 4; ++r)
        #pragma unroll
        for (int p = 0; p < 3; ++p)
          ps[r][p] += __shfl_xor(ps[r][p], mask, 64);

    if (l15 == 0) {
      int row = i * 16 + quad * 4;               // +r below
      #pragma unroll
      for (int r = 0; r < 4; ++r)
        #pragma unroll
        for (int p = 0; p < 3; ++p)
          scr[wid * 192 + (row + r) * 3 + p] = ps[r][p];
    }
  }
  __syncthreads();

  // 192 threads: final value = sum of 4 wave partials + b2 -> out
  if (tid < 192) {
    int rl = tid / 3, p = tid - rl * 3;          // rl 0..63
    float v = scr[rl * 3 + p] + scr[192 + rl * 3 + p]
            + scr[384 + rl * 3 + p] + scr[576 + rl * 3 + p]
            + b2[head * 3 + p];
    out[(size_t)(m0 + rl) * (N_HEADS * 3) + head * 3 + p] = v;
  }
}

extern "C" void kernel_launch(void* const* d_in, const int* in_sizes, int n_in,
                              void* d_out, int out_size, void* d_ws, size_t ws_size,
                              hipStream_t stream) {
  const float* X  = (const float*)d_in[0];
  const float* W1 = (const float*)d_in[1];
  const float* b1 = (const float*)d_in[2];
  const float* W2 = (const float*)d_in[3];
  const float* b2 = (const float*)d_in[4];

  // ws: Xb 46,137,344 | W1T 23,068,672  = 69,206,016 B (proven fits)
  u16* Xb  = (u16*)d_ws;
  u16* W1T = (u16*)((char*)d_ws + (size_t)BATCH * D_IN * 2);

  convert_x<<<(BATCH * D_IN / 4) / 256, 256, 0, stream>>>(
      (const float4*)X, (ushort4*)Xb);

  transpose_w1<<<dim3(D_IN / 64, D_HID / 64, N_HEADS), dim3(64, 4), 0, stream>>>(W1, W1T);

  mano_gemm<<<dim3(BATCH / BM * N_HEADS), 256, 0, stream>>>(
      Xb, W1T, b1, W2, b2, (float*)d_out);
}